// Round 1
// 139.540 us; speedup vs baseline: 1.0008x; 1.0008x over previous
//
#include <hip/hip_runtime.h>

#define IN_F 256
#define OUT_F 64
#define NBKT_MAX 1024          // buckets of 64 dst nodes; supports N <= 65536
#define PART_BLOCKS 128
#define CAP 3072               // LDS edge capacity per bucket (mean ~1023, max ~1150)
#define DSTBUF_CAP 7168        // (32768 - 4096)/4 ints of staged dst per chunk

typedef __attribute__((ext_vector_type(8))) short short8;
typedef __attribute__((ext_vector_type(4))) float f32x4;
typedef unsigned int uint32;

#define AS_I(f) __builtin_bit_cast(int, f)
#define AS_F(i) __builtin_bit_cast(float, i)
#define DPP_ADD(v, ctrl, rmask) \
    v += AS_F(__builtin_amdgcn_update_dpp(0, AS_I(v), ctrl, rmask, 0xf, true))

// Per-half (32-lane) sum: row_shr 1/2/4/8 + row_bcast:15 -> lane31 = low-half
// sum, lane63 = high-half sum. Select by half. Pure VALU pipe (DPP).
__device__ __forceinline__ float half_sum_sel(float p, bool hi) {
    DPP_ADD(p, 0x111, 0xf);
    DPP_ADD(p, 0x112, 0xf);
    DPP_ADD(p, 0x114, 0xf);
    DPP_ADD(p, 0x118, 0xf);
    DPP_ADD(p, 0x142, 0xa);
    float dlo = AS_F(__builtin_amdgcn_readlane(AS_I(p), 31));
    float dhi = AS_F(__builtin_amdgcn_readlane(AS_I(p), 63));
    return hi ? dhi : dlo;
}

__device__ __forceinline__ unsigned short f2bf(float f) {  // RNE f32->bf16
    uint32 u = __builtin_bit_cast(uint32, f);
    u += 0x7fffu + ((u >> 16) & 1u);
    return (unsigned short)(u >> 16);
}
__device__ __forceinline__ float bf2f(unsigned short s) {
    return __builtin_bit_cast(float, (uint32)s << 16);
}

// ---------------------------------------------------------------------------
// FUSED gemm + segment-table partition, 512 thr (8 waves).
// Blocks [0, PART_BLOCKS): partition own edge chunk into bucket-grouped runs.
//   NEW: dst staged in LDS during count pass; place pass reads it from LDS
//   (removes one 3.2 MB global pass over dst).
// Blocks [PART_BLOCKS, ...): MFMA gemm, 256 rows/block (8 waves x 32 rows) --
//   halves block count and redundant w-staging traffic vs the 128-row version.
// ---------------------------------------------------------------------------
__global__ __launch_bounds__(512) void gemm_part_kernel(const float* __restrict__ h,
                                                        const float* __restrict__ w,
                                                        unsigned short* __restrict__ hpb,
                                                        int N,
                                                        const int* __restrict__ src,
                                                        const int* __restrict__ dst,
                                                        int* __restrict__ tbl,
                                                        uint32* __restrict__ pairs,
                                                        int E, int NB) {
    __shared__ char smem[32768];          // union: lcnt+dstbuf (partition) / wfrag (gemm)
    __shared__ int wsum[8];
    int b = blockIdx.x, t = threadIdx.x;

    if (b < PART_BLOCKS) {
        // ---- partition path ----
        int* lcnt   = (int*)smem;                  // [NBKT_MAX] counts, then cursors
        int* dstbuf = (int*)smem + NBKT_MAX;       // [DSTBUF_CAP] staged dst values
        int lane = t & 63, wid = t >> 6;
        int chunk = (E + PART_BLOCKS - 1) / PART_BLOCKS;
        int s0 = b * chunk, s1 = min(E, s0 + chunk);
        bool stageDst = (s1 - s0) <= DSTBUF_CAP;

        for (int i = t; i < NB; i += 512) lcnt[i] = 0;
        __syncthreads();
        if (stageDst) {
            for (int e = s0 + t; e < s1; e += 512) {
                int d = dst[e];
                dstbuf[e - s0] = d;
                atomicAdd(&lcnt[d >> 6], 1);
            }
        } else {
            for (int e = s0 + t; e < s1; e += 512)
                atomicAdd(&lcnt[dst[e] >> 6], 1);
        }
        __syncthreads();

        // exclusive scan of lcnt (2 consecutive values/thread, scalar locals)
        int i0 = t * 2;
        int x0 = (i0     < NB) ? lcnt[i0]     : 0;
        int x1 = (i0 + 1 < NB) ? lcnt[i0 + 1] : 0;
        int s  = x0 + x1;
        int xs = s;
#pragma unroll
        for (int off = 1; off < 64; off <<= 1) {
            int y = __shfl_up(xs, off, 64);
            if (lane >= off) xs += y;
        }
        if (lane == 63) wsum[wid] = xs;
        __syncthreads();                  // all lcnt reads done before overwrite
        int basew = 0;
        for (int k = 0; k < wid; ++k) basew += wsum[k];
        int toff = basew + xs - s;

        int* trow = tbl + (size_t)b * (NB + 1);
        if (i0     < NB) { trow[i0]     = s0 + toff;      lcnt[i0]     = toff;      }
        if (i0 + 1 < NB) { trow[i0 + 1] = s0 + toff + x0; lcnt[i0 + 1] = toff + x0; }
        if (t == 0) trow[NB] = s1;
        __syncthreads();

        // place pass: lcnt is now the per-bucket cursor (chunk-relative)
        for (int e = s0 + t; e < s1; e += 512) {
            int d  = stageDst ? dstbuf[e - s0] : dst[e];
            int bk = d >> 6;
            int idx = atomicAdd(&lcnt[bk], 1);
            pairs[s0 + idx] = (uint32)src[e] | ((uint32)(d & 63) << 26);
        }
        return;
    }

    // ---- gemm path: 256 rows/block, 8 waves x 32 rows (2 M-tiles/wave) ----
    int gb = b - PART_BLOCKS;
    short8* wfrag = (short8*)smem;        // 2048 slots * 16B = 32 KB
    for (int slot = t; slot < 2048; slot += 512) {
        int kb = slot >> 6, n = slot & 63;
        short8 v;
#pragma unroll
        for (int jj = 0; jj < 8; ++jj)
            v[jj] = (short)f2bf(w[(size_t)(kb * 8 + jj) * OUT_F + n]);
        wfrag[slot] = v;
    }
    __syncthreads();

    int wave = t >> 6, lane = t & 63;
    int n16  = lane & 15, quad = lane >> 4;
    int base = gb * 256 + wave * 32;
    int ra = base + n16;      if (ra >= N) ra = N - 1;
    int rb = base + 16 + n16; if (rb >= N) rb = N - 1;
    const float* arow0 = h + (size_t)ra * IN_F;
    const float* arow1 = h + (size_t)rb * IN_F;

    f32x4 acc[2][4];
#pragma unroll
    for (int m = 0; m < 2; ++m)
#pragma unroll
        for (int ct = 0; ct < 4; ++ct) acc[m][ct] = (f32x4){0.f, 0.f, 0.f, 0.f};

#pragma unroll
    for (int ks = 0; ks < 8; ++ks) {
        int k0 = ks * 32;
        float4 a0 = *(const float4*)(arow0 + k0 + quad * 8);
        float4 a1 = *(const float4*)(arow0 + k0 + quad * 8 + 4);
        float4 b0 = *(const float4*)(arow1 + k0 + quad * 8);
        float4 b1 = *(const float4*)(arow1 + k0 + quad * 8 + 4);
        short8 af, ag;
        af[0] = (short)f2bf(a0.x); af[1] = (short)f2bf(a0.y);
        af[2] = (short)f2bf(a0.z); af[3] = (short)f2bf(a0.w);
        af[4] = (short)f2bf(a1.x); af[5] = (short)f2bf(a1.y);
        af[6] = (short)f2bf(a1.z); af[7] = (short)f2bf(a1.w);
        ag[0] = (short)f2bf(b0.x); ag[1] = (short)f2bf(b0.y);
        ag[2] = (short)f2bf(b0.z); ag[3] = (short)f2bf(b0.w);
        ag[4] = (short)f2bf(b1.x); ag[5] = (short)f2bf(b1.y);
        ag[6] = (short)f2bf(b1.z); ag[7] = (short)f2bf(b1.w);
        int kb = ks * 4 + quad;
#pragma unroll
        for (int ct = 0; ct < 4; ++ct) {
            short8 bw = wfrag[kb * 64 + ct * 16 + n16];
            acc[0][ct] = __builtin_amdgcn_mfma_f32_16x16x32_bf16(af, bw, acc[0][ct], 0, 0, 0);
            acc[1][ct] = __builtin_amdgcn_mfma_f32_16x16x32_bf16(ag, bw, acc[1][ct], 0, 0, 0);
        }
    }

#pragma unroll
    for (int m = 0; m < 2; ++m) {
#pragma unroll
        for (int ct = 0; ct < 4; ++ct) {
#pragma unroll
            for (int r = 0; r < 4; ++r) {
                int ro = base + m * 16 + quad * 4 + r;
                if (ro < N) hpb[(size_t)ro * OUT_F + ct * 16 + n16] = f2bf(acc[m][ct][r]);
            }
        }
    }
}

// ---------------------------------------------------------------------------
// FUSED gather+sort+accumulate: block = bucket of 64 dst nodes, 512 thr.
// 1) read 128 segment descriptors (tbl column), wave-scan lengths -> psum;
// 2) stage bucket's edges from 128 pair-runs into LDS (binary search psum)
//    FUSED with bin counting (one fewer LDS pass + barrier vs before);
// 3) scan bins + scatter to slds (counting sort by dstLocal);
// 4) per-node wave accumulate: lanes 0-31 = even edge, 32-63 = odd edge,
//    lane = 2 bf16 features -> one dword gather serves two edge rows;
//    16-edge batches, ALL SCALAR STATE; hd for node k+1 prefetched during k.
// Fallback nE > CAP: filtered scan over segments (correctness only).
// ---------------------------------------------------------------------------
#define GATH(S) (*(const uint32*)(hpb + (size_t)(S) * OUT_F + half * 2))
#define PROC(Q) { float a0 = bf2f((unsigned short)((Q) & 0xffff));            \
                  float a1 = bf2f((unsigned short)((Q) >> 16));               \
                  float dd = half_sum_sel(fmaf(a1, hd1, a0 * hd0), hi);       \
                  acc0 = fmaf(dd, a0, acc0); acc1 = fmaf(dd, a1, acc1); }

__global__ __launch_bounds__(512) void accum_kernel(const unsigned short* __restrict__ hpb,
                                                    const uint32* __restrict__ pairs,
                                                    const int* __restrict__ tbl,
                                                    const float* __restrict__ attw,
                                                    float* __restrict__ out, int N, int NB) {
    __shared__ uint32 sraw[CAP];
    __shared__ int slds[CAP];
    __shared__ int segb[PART_BLOCKS], slen[PART_BLOCKS], psum[PART_BLOCKS + 1];
    __shared__ int bin[64], excl[65], cur[64];

    int b = blockIdx.x, t = threadIdx.x;
    int wid = t >> 6, lane = t & 63;
    int half = lane & 31;
    bool hi  = lane >= 32;
    int node0 = b * 64;

    // ---- segment descriptors ----
    if (t < PART_BLOCKS) {
        const int* trow = tbl + (size_t)t * (NB + 1);
        int b0 = trow[b];
        segb[t] = b0;
        slen[t] = trow[b + 1] - b0;
    }
    __syncthreads();
    if (wid == 0) {                       // wave-0 exclusive scan of 128 lengths
        int l0 = slen[lane * 2], l1 = slen[lane * 2 + 1];
        int s = l0 + l1, xs = s;
#pragma unroll
        for (int off = 1; off < 64; off <<= 1) {
            int y = __shfl_up(xs, off, 64);
            if (lane >= off) xs += y;
        }
        int ex = xs - s;
        psum[lane * 2]     = ex;
        psum[lane * 2 + 1] = ex + l0;
        if (lane == 63) psum[PART_BLOCKS] = xs;
    }
    if (wid == 1) bin[lane] = 0;          // zero bins in parallel with the scan
    __syncthreads();
    int nE = psum[PART_BLOCKS];

    float c = 0.f;
#pragma unroll
    for (int i = 0; i < 8; ++i) c += attw[i];

    if (nE <= CAP) {
        // ---- stage + count fused: binary search psum, load pair, count bin ----
        for (int i = t; i < nE; i += 512) {
            int lo = 0, hh = PART_BLOCKS - 1;
#pragma unroll
            for (int it = 0; it < 7; ++it) {   // 2^7 = 128
                int mid = (lo + hh + 1) >> 1;
                if (psum[mid] <= i) lo = mid; else hh = mid - 1;
            }
            uint32 p = pairs[segb[lo] + (i - psum[lo])];
            sraw[i] = p;
            atomicAdd(&bin[p >> 26], 1);
        }
        __syncthreads();
        if (t < 64) {
            int v = bin[t], x = v;
#pragma unroll
            for (int off = 1; off < 64; off <<= 1) {
                int y = __shfl_up(x, off, 64);
                if (t >= off) x += y;
            }
            excl[t] = x - v;
            cur[t]  = x - v;
            if (t == 63) excl[64] = x;
        }
        __syncthreads();
        for (int i = t; i < nE; i += 512) {
            uint32 p = sraw[i];
            int pos = atomicAdd(&cur[(int)(p >> 26)], 1);
            slds[pos] = (int)(p & 0x3FFFFFFu);
        }
        __syncthreads();

        // ---- accumulate: wave wid handles nodes wid + 8k; hd prefetched ----
        int a0i = min(node0 + wid, N - 1);
        uint32 hd2 = *(const uint32*)(hpb + (size_t)a0i * OUT_F + half * 2);
#pragma unroll 1
        for (int k = 0; k < 8; ++k) {
            int node = node0 + wid + 8 * k;
            uint32 hd2n = 0;
            if (k < 7) {                  // prefetch next node's hd during this node
                int an = min(node + 8, N - 1);
                hd2n = *(const uint32*)(hpb + (size_t)an * OUT_F + half * 2);
            }
            if (node < N) {
                int n  = wid + 8 * k;
                int jb = excl[n], je = excl[n + 1];

                float hd0 = bf2f((unsigned short)(hd2 & 0xffff));
                float hd1 = bf2f((unsigned short)(hd2 >> 16));

                float acc0 = 0.f, acc1 = 0.f;
                int j = jb;
                int sel = hi ? 1 : 0;

                for (; j + 16 <= je; j += 16) {      // 8 gathers = 16 edges in flight
                    int i0 = slds[j + 0  + sel], i1 = slds[j + 2  + sel];
                    int i2 = slds[j + 4  + sel], i3 = slds[j + 6  + sel];
                    int i4 = slds[j + 8  + sel], i5 = slds[j + 10 + sel];
                    int i6 = slds[j + 12 + sel], i7 = slds[j + 14 + sel];
                    uint32 q0 = GATH(i0), q1 = GATH(i1), q2 = GATH(i2), q3 = GATH(i3);
                    uint32 q4 = GATH(i4), q5 = GATH(i5), q6 = GATH(i6), q7 = GATH(i7);
                    PROC(q0) PROC(q1) PROC(q2) PROC(q3)
                    PROC(q4) PROC(q5) PROC(q6) PROC(q7)
                }
                for (; j + 8 <= je; j += 8) {        // 4 gathers = 8 edges
                    int i0 = slds[j + 0 + sel], i1 = slds[j + 2 + sel];
                    int i2 = slds[j + 4 + sel], i3 = slds[j + 6 + sel];
                    uint32 q0 = GATH(i0), q1 = GATH(i1), q2 = GATH(i2), q3 = GATH(i3);
                    PROC(q0) PROC(q1) PROC(q2) PROC(q3)
                }
                for (; j + 2 <= je; j += 2) {
                    int i0 = slds[j + sel];
                    uint32 q0 = GATH(i0);
                    PROC(q0)
                }
                if (j < je) {                        // odd final edge: low half only
                    int i0 = slds[j];
                    uint32 q0 = GATH(i0);
                    float a0 = bf2f((unsigned short)(q0 & 0xffff));
                    float a1 = bf2f((unsigned short)(q0 >> 16));
                    float dd = half_sum_sel(fmaf(a1, hd1, a0 * hd0), false);
                    if (!hi) {
                        acc0 = fmaf(dd, a0, acc0);
                        acc1 = fmaf(dd, a1, acc1);
                    }
                }

                acc0 += __shfl_xor(acc0, 32, 64);
                acc1 += __shfl_xor(acc1, 32, 64);

                if (!hi) {
                    float r0, r1;
                    if (je > jb) { r0 = acc0 * c; r1 = acc1 * c; }
                    else         { r0 = hd0;      r1 = hd1;      }
                    *(float2*)(out + (size_t)node * OUT_F + half * 2) = make_float2(r0, r1);
                }
            }
            hd2 = hd2n;
        }
    } else {
        // ---- fallback (correctness only; not expected for uniform dst) ----
#pragma unroll 1
        for (int k = 0; k < 8; ++k) {
            int n    = wid + 8 * k;
            int node = node0 + n;
            if (node >= N) continue;

            uint32 hd2 = *(const uint32*)(hpb + (size_t)node * OUT_F + half * 2);
            float hd0 = bf2f((unsigned short)(hd2 & 0xffff));
            float hd1 = bf2f((unsigned short)(hd2 >> 16));

            float acc0 = 0.f, acc1 = 0.f;
            int deg = 0;
            for (int p = 0; p < PART_BLOCKS; ++p) {
                int bb = segb[p], ee = bb + slen[p];
                for (int i = bb; i < ee; ++i) {
                    uint32 pr = pairs[i];
                    if ((int)(pr >> 26) == n) {
                        ++deg;
                        uint32 q0 = GATH((int)(pr & 0x3FFFFFFu));
                        float a0 = bf2f((unsigned short)(q0 & 0xffff));
                        float a1 = bf2f((unsigned short)(q0 >> 16));
                        float dd = half_sum_sel(fmaf(a1, hd1, a0 * hd0), false);
                        if (!hi) {
                            acc0 = fmaf(dd, a0, acc0);
                            acc1 = fmaf(dd, a1, acc1);
                        }
                    }
                }
            }
            acc0 += __shfl_xor(acc0, 32, 64);
            acc1 += __shfl_xor(acc1, 32, 64);
            if (!hi) {
                float r0, r1;
                if (deg > 0) { r0 = acc0 * c; r1 = acc1 * c; }
                else         { r0 = hd0;      r1 = hd1;      }
                *(float2*)(out + (size_t)node * OUT_F + half * 2) = make_float2(r0, r1);
            }
        }
    }
}

extern "C" void kernel_launch(void* const* d_in, const int* in_sizes, int n_in,
                              void* d_out, int out_size, void* d_ws, size_t ws_size,
                              hipStream_t stream) {
    const float* h    = (const float*)d_in[0];
    const float* w    = (const float*)d_in[1];
    const float* attw = (const float*)d_in[2];
    const int*   src  = (const int*)d_in[3];
    const int*   dst  = (const int*)d_in[4];

    int N = in_sizes[0] / IN_F;
    int E = in_sizes[3];
    int NB = (N + 63) >> 6;    // 782 for N=50000 (NB <= NBKT_MAX)
    int ngemm = (N + 255) / 256;

    float* out = (float*)d_out;

    char* p = (char*)d_ws;
    unsigned short* hpb = (unsigned short*)p;  p += (size_t)N * OUT_F * sizeof(unsigned short);
    int* tbl      = (int*)p;                   p += (size_t)PART_BLOCKS * (NBKT_MAX + 1) * sizeof(int);
    uint32* pairs = (uint32*)p;

    // no memset needed: all global scratch is fully written before being read
    gemm_part_kernel<<<PART_BLOCKS + ngemm, 512, 0, stream>>>(h, w, hpb, N,
                                                              src, dst, tbl, pairs, E, NB);

    accum_kernel<<<NB, 512, 0, stream>>>(hpb, pairs, tbl, attw, out, N, NB);
}